// Round 18
// baseline (848.968 us; speedup 1.0000x reference)
//
#include <hip/hip_runtime.h>
#include <hip/hip_bf16.h>
#include <cstddef>

typedef __bf16 bf16;
typedef __attribute__((ext_vector_type(8))) __bf16 bf16x8;
typedef __attribute__((ext_vector_type(4))) __bf16 bf16x4;
typedef __attribute__((ext_vector_type(4))) float f32x4;

constexpr int VOC = 32000;
constexpr int DIM = 512;
constexpr int NH  = 8;
constexpr int HSZ = 64;
constexpr int SEQ = 2048;
constexpr int NB  = 2;
constexpr int NL  = 4;
constexpr int NTOK = NB * SEQ;   // 4096 rows
constexpr int QS  = 3 * DIM;     // qkv weight N
constexpr int QKS = 2 * DIM;     // packed q|k row stride

// async global->LDS, 16B per lane (wave-uniform LDS base + lane*16)
__device__ __forceinline__ void gload16(const void* g, void* lds) {
  __builtin_amdgcn_global_load_lds(
      (const __attribute__((address_space(1))) unsigned int*)g,
      (__attribute__((address_space(3))) unsigned int*)lds, 16, 0, 0);
}

// -------------------------------------- mega: emln rows + ALL weight transposes
__global__ __launch_bounds__(256) void wt_emln(
    const int* __restrict__ idx, const float* __restrict__ tok,
    const float* __restrict__ pos, const float* __restrict__ g1,
    const float* __restrict__ b1v, float* __restrict__ x, bf16* __restrict__ h,
    const float* __restrict__ wq, const float* __restrict__ wk,
    const float* __restrict__ wv, const float* __restrict__ wo,
    const float* __restrict__ w1, const float* __restrict__ w2,
    const float* __restrict__ hw,
    bf16* __restrict__ wqkvT, bf16* __restrict__ woT,
    bf16* __restrict__ w1T, bf16* __restrict__ w2T, bf16* __restrict__ headT) {
  __shared__ float t[64][65];
  __shared__ float s1[4], s2[4];
  int bid = blockIdx.x;
  int tid = threadIdx.x;
  if (bid < NTOK) {
    int row = bid;
    int lane = tid & 63, w = tid >> 6;
    int tt = row & (SEQ - 1);
    int tk = idx[row];
    float a0 = tok[(size_t)tk * DIM + tid] + pos[(size_t)tt * DIM + tid];
    float a1 = tok[(size_t)tk * DIM + tid + 256] + pos[(size_t)tt * DIM + tid + 256];
    x[(size_t)row * DIM + tid] = a0;
    x[(size_t)row * DIM + tid + 256] = a1;
    float ps = a0 + a1, pq = a0 * a0 + a1 * a1;
#pragma unroll
    for (int m = 1; m < 64; m <<= 1) {
      ps += __shfl_xor(ps, m, 64);
      pq += __shfl_xor(pq, m, 64);
    }
    if (lane == 0) { s1[w] = ps; s2[w] = pq; }
    __syncthreads();
    float fs = s1[0] + s1[1] + s1[2] + s1[3];
    float fq = s2[0] + s2[1] + s2[2] + s2[3];
    float mu = fs * (1.0f / DIM);
    float var = fq * (1.0f / DIM) - mu * mu;
    float rs = rsqrtf(var + 1e-5f);
    h[(size_t)row * DIM + tid] = (bf16)((a0 - mu) * rs * g1[tid] + b1v[tid]);
    h[(size_t)row * DIM + tid + 256] =
        (bf16)((a1 - mu) * rs * g1[tid + 256] + b1v[tid + 256]);
    return;
  }
  int wb = bid - NTOK;
  const float* src; bf16* dst; int K, N, n0, k0;
  if (wb < 3072) {
    int l = wb / 768, tt = wb - l * 768;
    if (tt < 256) {
      int which = tt >> 6, u = tt & 63;
      K = DIM; N = DIM;
      n0 = (u & 7) * 64; k0 = (u >> 3) * 64;
      if (which == 0)      { src = wq + (size_t)l * DIM * DIM; dst = wqkvT + (size_t)l * QS * DIM; }
      else if (which == 1) { src = wk + (size_t)l * DIM * DIM; dst = wqkvT + (size_t)l * QS * DIM + DIM * DIM; }
      else if (which == 2) { src = wv + (size_t)l * DIM * DIM; dst = wqkvT + (size_t)l * QS * DIM + 2 * DIM * DIM; }
      else                 { src = wo + (size_t)l * DIM * DIM; dst = woT + (size_t)l * DIM * DIM; }
    } else if (tt < 512) {
      int u = tt - 256;
      K = DIM; N = 4 * DIM;
      n0 = (u & 31) * 64; k0 = (u >> 5) * 64;
      src = w1 + (size_t)l * DIM * 4 * DIM; dst = w1T + (size_t)l * 4 * DIM * DIM;
    } else {
      int u = tt - 512;
      K = 4 * DIM; N = DIM;
      n0 = (u & 7) * 64; k0 = (u >> 3) * 64;
      src = w2 + (size_t)l * 4 * DIM * DIM; dst = w2T + (size_t)l * 4 * DIM * DIM;
    }
  } else {
    int u = wb - 3072;
    K = DIM; N = VOC;
    n0 = (u >> 3) * 64; k0 = (u & 7) * 64;
    src = hw; dst = headT;
  }
  int tx = tid & 63, ty = tid >> 6;
#pragma unroll
  for (int r = 0; r < 16; ++r) {
    int row = ty + r * 4;
    t[row][tx] = src[(size_t)(k0 + row) * N + n0 + tx];
  }
  __syncthreads();
#pragma unroll
  for (int r = 0; r < 16; ++r) {
    int row = ty + r * 4;
    dst[(size_t)(n0 + row) * K + k0 + tx] = (bf16)t[tx][row];
  }
}

// ------------------------------------------- layernorm: wave-per-row, 4/block
__global__ __launch_bounds__(256) void ln_kernel(
    const float* __restrict__ x, const float* __restrict__ g,
    const float* __restrict__ b, bf16* __restrict__ out) {
  int row = blockIdx.x * 4 + (threadIdx.x >> 6);
  int lane = threadIdx.x & 63;
  const float* xr = x + (size_t)row * DIM + lane * 8;
  float4 v0 = *(const float4*)xr;
  float4 v1 = *(const float4*)(xr + 4);
  float ps = v0.x + v0.y + v0.z + v0.w + v1.x + v1.y + v1.z + v1.w;
  float pq = v0.x * v0.x + v0.y * v0.y + v0.z * v0.z + v0.w * v0.w +
             v1.x * v1.x + v1.y * v1.y + v1.z * v1.z + v1.w * v1.w;
#pragma unroll
  for (int m = 1; m < 64; m <<= 1) {
    ps += __shfl_xor(ps, m, 64);
    pq += __shfl_xor(pq, m, 64);
  }
  float mu = ps * (1.0f / DIM);
  float var = pq * (1.0f / DIM) - mu * mu;
  float rs = rsqrtf(var + 1e-5f);
  const float* gp = g + lane * 8;
  const float* bp = b + lane * 8;
  float4 g0 = *(const float4*)gp, g1v = *(const float4*)(gp + 4);
  float4 b0 = *(const float4*)bp, b1v = *(const float4*)(bp + 4);
  bf16x8 o;
  o[0] = (bf16)((v0.x - mu) * rs * g0.x + b0.x);
  o[1] = (bf16)((v0.y - mu) * rs * g0.y + b0.y);
  o[2] = (bf16)((v0.z - mu) * rs * g0.z + b0.z);
  o[3] = (bf16)((v0.w - mu) * rs * g0.w + b0.w);
  o[4] = (bf16)((v1.x - mu) * rs * g1v.x + b1v.x);
  o[5] = (bf16)((v1.y - mu) * rs * g1v.y + b1v.y);
  o[6] = (bf16)((v1.z - mu) * rs * g1v.z + b1v.z);
  o[7] = (bf16)((v1.w - mu) * rs * g1v.w + b1v.w);
  *(bf16x8*)(out + (size_t)row * DIM + lane * 8) = o;
}

// ------------------------------------------------------------- GEMM BMxBN
// 2-barrier m97 loop. DB=true: counted-vmcnt double-buffer — only where
// occupancy arithmetic shows no loss (QKV/wo/ffn1/ffn2, <=2 blocks/CU).
// Head: BN=256, 8 waves, single-buffered (A/B-confirmed best at K=512).
template <int BM, int BN, bool RELU, bool RES, bool OUTB, bool VSPLIT, bool DB>
__global__ __launch_bounds__((BN == 256) ? 512 : 256) void gemm_t(
    const bf16* __restrict__ A, const bf16* __restrict__ Wt,
    const float* __restrict__ bias, const float* __restrict__ res,
    float* __restrict__ outF, bf16* __restrict__ outB, bf16* __restrict__ vTout,
    int K, int N, int ostride) {
  constexpr int NW = (BN == 256) ? 8 : 4;
  constexpr int WN = (BN == 256) ? 4 : (BN == 128) ? 2 : 1;
  constexpr int WM = NW / WN;
  constexpr int MP = BM / WM / 16;
  constexpr int NP = BN / WN / 16;
  constexpr int AJ = (BM * 128) / (NW * 1024);
  constexpr int BJ = (BN * 128) / (NW * 1024);
  constexpr int VC = AJ + BJ;
  static_assert(!DB || VC == 6 || VC == 8, "DB vmcnt supports 6 or 8 loads");
  __shared__ bf16 As[(DB ? 2 : 1) * BM * 64];
  __shared__ bf16 Bs[(DB ? 2 : 1) * BN * 64];
  int tid = threadIdx.x;
  int wid = tid >> 6, ln = tid & 63;
  int lr = ln & 15, lg = ln >> 4;
  int nmt = gridDim.x;
  int bid = blockIdx.y * nmt + blockIdx.x;
  int cpx = (gridDim.x * gridDim.y) >> 3;
  int swz = (bid & 7) * cpx + (bid >> 3);
  int m0 = (swz % nmt) * BM;
  int n0 = (swz / nmt) * BN;
  int wr = wid / WN, wc = wid % WN;
  f32x4 acc[MP][NP] = {};

  const char* Ab = (const char*)A;
  const char* Bb = (const char*)Wt;

  auto STAGE = [&](int k0s, int buf) {
#pragma unroll
    for (int j = 0; j < AJ; ++j) {
      int Lb = j * (NW * 1024) + wid * 1024;
      int L = Lb + ln * 16;
      int row = L >> 7;
      int colb = (L & 127) ^ ((row & 7) << 4);
      gload16(Ab + (size_t)(m0 + row) * (K * 2) + (size_t)k0s * 2 + colb,
              (char*)As + buf * (BM * 128) + Lb);
    }
#pragma unroll
    for (int j = 0; j < BJ; ++j) {
      int Lb = j * (NW * 1024) + wid * 1024;
      int L = Lb + ln * 16;
      int row = L >> 7;
      int colb = (L & 127) ^ ((row & 7) << 4);
      gload16(Bb + (size_t)(n0 + row) * (K * 2) + (size_t)k0s * 2 + colb,
              (char*)Bs + buf * (BN * 128) + Lb);
    }
  };

  if (DB) STAGE(0, 0);
  int cur = 0;
  for (int k0 = 0; k0 < K; k0 += 64) {
    if (!DB) {
      __syncthreads();
      STAGE(k0, 0);
      __syncthreads();
    } else {
      if (k0 + 64 < K) {
        STAGE(k0 + 64, cur ^ 1);
        if constexpr (VC == 6)
          asm volatile("s_waitcnt vmcnt(6)" ::: "memory");
        else
          asm volatile("s_waitcnt vmcnt(8)" ::: "memory");
      } else {
        asm volatile("s_waitcnt vmcnt(0)" ::: "memory");
      }
      __builtin_amdgcn_s_barrier();
    }
#pragma unroll
    for (int kk = 0; kk < 2; ++kk) {
      bf16x8 am[MP], bn[NP];
#pragma unroll
      for (int m = 0; m < MP; ++m) {
        int row = wr * (BM / WM) + m * 16 + lr;
        int cb = (kk * 64 + lg * 16) ^ ((row & 7) << 4);
        am[m] = *(const bf16x8*)((const char*)As + cur * (BM * 128) + row * 128 + cb);
      }
#pragma unroll
      for (int n = 0; n < NP; ++n) {
        int row = wc * (BN / WN) + n * 16 + lr;
        int cb = (kk * 64 + lg * 16) ^ ((row & 7) << 4);
        bn[n] = *(const bf16x8*)((const char*)Bs + cur * (BN * 128) + row * 128 + cb);
      }
#pragma unroll
      for (int m = 0; m < MP; ++m)
#pragma unroll
        for (int n = 0; n < NP; ++n)
          acc[m][n] = __builtin_amdgcn_mfma_f32_16x16x32_bf16(
              am[m], bn[n], acc[m][n], 0, 0, 0);
    }
    if (DB) {
      __builtin_amdgcn_s_barrier();
      cur ^= 1;
    }
  }

  if (VSPLIT && n0 >= 2 * DIM) {
#pragma unroll
    for (int m = 0; m < MP; ++m) {
      int mrow = m0 + wr * (BM / WM) + m * 16 + lg * 4;
      int bb = mrow >> 11, tt = mrow & (SEQ - 1);
#pragma unroll
      for (int n = 0; n < NP; ++n) {
        int d = n0 + wc * (BN / WN) + n * 16 + lr - 2 * DIM;
        bf16x4 pk;
#pragma unroll
        for (int i = 0; i < 4; ++i) pk[i] = (bf16)acc[m][n][i];
        *(bf16x4*)(vTout + ((size_t)(bb * NH + (d >> 6)) * HSZ + (d & 63)) * SEQ + tt) = pk;
      }
    }
    return;
  }

  float qscale = (VSPLIT && n0 < DIM) ? 0.125f : 1.0f;
#pragma unroll
  for (int m = 0; m < MP; ++m) {
    int mrow = m0 + wr * (BM / WM) + m * 16 + lg * 4;
#pragma unroll
    for (int n = 0; n < NP; ++n) {
      int nc = n0 + wc * (BN / WN) + n * 16 + lr;
      float bval = bias ? bias[nc] : 0.0f;
#pragma unroll
      for (int i = 0; i < 4; ++i) {
        int mm = mrow + i;
        float val = acc[m][n][i] * qscale + bval;
        if (RELU) val = fmaxf(val, 0.0f);
        if (RES) val += res[(size_t)mm * ostride + nc];
        if (OUTB) outB[(size_t)mm * ostride + nc] = (bf16)val;
        else      outF[(size_t)mm * ostride + nc] = val;
      }
    }
  }
}

// ---------------------------------------------------------------- flash attn
// QBLK=128: 256 blocks, 8 waves each, KVBLK=64 — halves K/V staging traffic
// (272 vs 528 tile-loads per (b,h)) and epilogue count vs QBLK=64.
// XCD remap + deterministic pairing (c,15-c) => 34 tiles per CU.
// dbuf K/V via gload16 + counted vmcnt(2). Max-free softmax; T5 setprio.
__global__ __launch_bounds__(512) void fattn_kernel(
    const bf16* __restrict__ qk, const bf16* __restrict__ vT,
    bf16* __restrict__ att) {
  __shared__ bf16 Ks[2][64 * 64];
  __shared__ bf16 Vs[2][64 * 64];
  __shared__ bf16 Pl[8][16][72];
  int tid = threadIdx.x;
  int wave = tid >> 6, lane = tid & 63;
  int lr = lane & 15, lg = lane >> 4;
  int linear = blockIdx.x + 16 * (blockIdx.y + 8 * blockIdx.z);  // 0..255
  int swz = (linear & 7) * 32 + (linear >> 3);                   // XCD chunks
  int qtile = swz & 15;
  int hb = swz >> 4;                 // 0..15
  if (hb & 1) qtile = 15 - qtile;    // pair: (2c+2)+(2(15-c)+2) = 34 tiles
  int h = hb & 7, b = hb >> 3;
  int qt0 = qtile * 128;
  const bf16* qb = qk + ((size_t)b * SEQ) * QKS + h * HSZ;
  const char* kb = (const char*)(qb + DIM);
  const char* vb = (const char*)(vT + (size_t)(b * NH + h) * HSZ * SEQ);

  bf16x8 aq[2];
  {
    const bf16* qr = qb + (size_t)(qt0 + wave * 16 + lr) * QKS + lg * 8;
    aq[0] = *(const bf16x8*)qr;
    aq[1] = *(const bf16x8*)(qr + 32);
  }

  f32x4 accO[4] = {};
  float l_r[4] = {0.f, 0.f, 0.f, 0.f};

  int ntile = 2 * qtile + 2;
  // 8 waves: each stages 1KB of K and 1KB of V per tile (2 gload16)
#define STAGE(ti, buf)                                                        \
  {                                                                           \
    int L = wave * 1024 + lane * 16;                                          \
    int row = L >> 7;                                                         \
    int cb = (L & 127) ^ ((row & 7) << 4);                                    \
    gload16(kb + (size_t)((ti) * 64 + row) * (QKS * 2) + cb,                  \
            (char*)Ks[buf] + wave * 1024);                                    \
    gload16(vb + (size_t)row * (SEQ * 2) + (ti) * 128 + cb,                   \
            (char*)Vs[buf] + wave * 1024);                                    \
  }

  STAGE(0, 0);
  int cur = 0;
  for (int ti = 0; ti < ntile; ++ti) {
    if (ti + 1 < ntile) {
      STAGE(ti + 1, cur ^ 1);
      asm volatile("s_waitcnt vmcnt(2)" ::: "memory");
    } else {
      asm volatile("s_waitcnt vmcnt(0)" ::: "memory");
    }
    __builtin_amdgcn_s_barrier();
    int kv0 = ti * 64;
    bool needmask = (kv0 + 63) > (qt0 + wave * 16);

    f32x4 sc[4];
    __builtin_amdgcn_s_setprio(1);
#pragma unroll
    for (int s = 0; s < 4; ++s) {
      int row = s * 16 + lr;
      const char* base = (const char*)Ks[cur] + row * 128;
      bf16x8 b0 = *(const bf16x8*)(base + ((lg * 16) ^ ((row & 7) << 4)));
      bf16x8 b1 = *(const bf16x8*)(base + ((64 + lg * 16) ^ ((row & 7) << 4)));
      f32x4 z = {};
      z = __builtin_amdgcn_mfma_f32_16x16x32_bf16(aq[0], b0, z, 0, 0, 0);
      sc[s] = __builtin_amdgcn_mfma_f32_16x16x32_bf16(aq[1], b1, z, 0, 0, 0);
    }
    __builtin_amdgcn_s_setprio(0);

    // max-free softmax (C layout: row = lg*4+i, col = lr)
#pragma unroll
    for (int i = 0; i < 4; ++i) {
      if (needmask) {
        int qrow = qt0 + wave * 16 + lg * 4 + i;
#pragma unroll
        for (int s = 0; s < 4; ++s) {
          int kvc = kv0 + s * 16 + lr;
          if (kvc > qrow) sc[s][i] = -1e30f;
        }
      }
      float rs = 0.f;
#pragma unroll
      for (int s = 0; s < 4; ++s) {
        float p = __expf(sc[s][i]);
        sc[s][i] = p;
        rs += p;
      }
      rs += __shfl_xor(rs, 1, 64);
      rs += __shfl_xor(rs, 2, 64);
      rs += __shfl_xor(rs, 4, 64);
      rs += __shfl_xor(rs, 8, 64);
      l_r[i] += rs;
    }

#pragma unroll
    for (int i = 0; i < 4; ++i)
#pragma unroll
      for (int s = 0; s < 4; ++s)
        Pl[wave][lg * 4 + i][s * 16 + lr] = (bf16)sc[s][i];
    bf16x8 pa0 = *(const bf16x8*)&Pl[wave][lr][lg * 8];
    bf16x8 pa1 = *(const bf16x8*)&Pl[wave][lr][32 + lg * 8];

    __builtin_amdgcn_s_setprio(1);
#pragma unroll
    for (int ds = 0; ds < 4; ++ds) {
      int row = ds * 16 + lr;
      const char* base = (const char*)Vs[cur] + row * 128;
      bf16x8 v0 = *(const bf16x8*)(base + ((lg * 16) ^ ((row & 7) << 4)));
      bf16x8 v1 = *(const bf16x8*)(base + ((64 + lg * 16) ^ ((row & 7) << 4)));
      accO[ds] = __builtin_amdgcn_mfma_f32_16x16x32_bf16(pa0, v0, accO[ds], 0, 0, 0);
      accO[ds] = __builtin_amdgcn_mfma_f32_16x16x32_bf16(pa1, v1, accO[ds], 0, 0, 0);
    }
    __builtin_amdgcn_s_setprio(0);
    __builtin_amdgcn_s_barrier();
    cur ^= 1;
  }
#undef STAGE

#pragma unroll
  for (int i = 0; i < 4; ++i) {
    float inv = 1.0f / l_r[i];
    size_t orow = ((size_t)b * SEQ + qt0 + wave * 16 + lg * 4 + i) * DIM + h * HSZ;
#pragma unroll
    for (int ds = 0; ds < 4; ++ds)
      att[orow + ds * 16 + lr] = (bf16)(accO[ds][i] * inv);
  }
}

// ---------------------------------------------------------------- launcher
extern "C" void kernel_launch(void* const* d_in, const int* in_sizes, int n_in,
                              void* d_out, int out_size, void* d_ws, size_t ws_size,
                              hipStream_t stream) {
  const int*   idx    = (const int*)d_in[0];
  const float* tok    = (const float*)d_in[1];
  const float* pos    = (const float*)d_in[2];
  const float* ln1_g  = (const float*)d_in[3];
  const float* ln1_b  = (const float*)d_in[4];
  const float* wq     = (const float*)d_in[5];
  const float* wk     = (const float*)d_in[6];
  const float* wv     = (const float*)d_in[7];
  const float* wo     = (const float*)d_in[8];
  const float* bo     = (const float*)d_in[9];
  const float* ln2_g  = (const float*)d_in[10];
  const float* ln2_b  = (const float*)d_in[11];
  const float* w1     = (const float*)d_in[12];
  const float* b1     = (const float*)d_in[13];
  const float* w2     = (const float*)d_in[14];
  const float* b2     = (const float*)d_in[15];
  const float* lnf_g  = (const float*)d_in[16];
  const float* lnf_b  = (const float*)d_in[17];
  const float* head_w = (const float*)d_in[18];
  const float* head_b = (const float*)d_in[19];

  char* W = (char*)d_ws;
  float* x     = (float*)(W);                 // [4096][512] f32    8 MB
  bf16*  h     = (bf16*)(W + 8388608);        // [4096][512]        4 MB
  bf16*  qk    = (bf16*)(W + 12582912);       // [4096][1024]       8 MB
  bf16*  vTb   = (bf16*)(W + 20971520);       // [2][8][64][2048]   4 MB
  bf16*  attb  = (bf16*)(W + 25165824);       // [4096][512]        4 MB
  bf16*  ffn   = (bf16*)(W + 29360128);       // [4096][2048]      16 MB
  bf16*  wqkvT = (bf16*)(W + 46137344);       // 4L x [1536][512]   6 MB
  bf16*  woT   = (bf16*)(W + 52428800);       // 4L x [512][512]    2 MB
  bf16*  w1T   = (bf16*)(W + 54525952);       // 4L x [2048][512]   8 MB
  bf16*  w2T   = (bf16*)(W + 62914560);       // 4L x [512][2048]   8 MB
  bf16*  headT = (bf16*)(W + 71303168);       // [32000][512]      ~31.3 MB

  wt_emln<<<NTOK + 3072 + 4000, 256, 0, stream>>>(
      idx, tok, pos, ln1_g, ln1_b, x, h,
      wq, wk, wv, wo, w1, w2, head_w, wqkvT, woT, w1T, w2T, headT);

  dim3 gQKV(NTOK / 128, QS / 128);        // (32, 12)
  dim3 gD64(NTOK / 128, DIM / 64);        // (32, 8)
  dim3 gF1(NTOK / 128, 4 * DIM / 128);    // (32, 16)
  dim3 gV(NTOK / 128, VOC / 256);         // (32, 125)  BN=256 head (confirmed)
  dim3 gA(SEQ / 128, NH, NB);             // (16, 8, 2) QBLK=128

  for (int l = 0; l < NL; ++l) {
    if (l > 0)
      ln_kernel<<<NTOK / 4, 256, 0, stream>>>(x, ln1_g + l * DIM, ln1_b + l * DIM, h);
    gemm_t<128, 128, false, false, true, true, true><<<gQKV, 256, 0, stream>>>(
        h, wqkvT + (size_t)l * QS * DIM, nullptr, nullptr, nullptr, qk, vTb,
        DIM, QS, QKS);
    fattn_kernel<<<gA, 512, 0, stream>>>(qk, vTb, attb);
    gemm_t<128, 64, false, true, false, false, true><<<gD64, 256, 0, stream>>>(
        attb, woT + (size_t)l * DIM * DIM, bo + l * DIM, x, x, nullptr, nullptr,
        DIM, DIM, DIM);
    ln_kernel<<<NTOK / 4, 256, 0, stream>>>(x, ln2_g + l * DIM, ln2_b + l * DIM, h);
    gemm_t<128, 128, true, false, true, false, true><<<gF1, 256, 0, stream>>>(
        h, w1T + (size_t)l * 4 * DIM * DIM, b1 + (size_t)l * 4 * DIM, nullptr,
        nullptr, ffn, nullptr, DIM, 4 * DIM, 4 * DIM);
    gemm_t<128, 64, false, true, false, false, true><<<gD64, 256, 0, stream>>>(
        ffn, w2T + (size_t)l * 4 * DIM * DIM, b2 + l * DIM, x, x, nullptr,
        nullptr, 4 * DIM, DIM, DIM);
  }

  ln_kernel<<<NTOK / 4, 256, 0, stream>>>(x, lnf_g, lnf_b, h);
  gemm_t<128, 256, false, false, false, false, false><<<gV, 512, 0, stream>>>(
      h, headT, head_b, nullptr, (float*)d_out, nullptr, nullptr, DIM, VOC, VOC);
}

// Round 19
// 799.177 us; speedup vs baseline: 1.0623x; 1.0623x over previous
//
#include <hip/hip_runtime.h>
#include <hip/hip_bf16.h>
#include <cstddef>

typedef __bf16 bf16;
typedef __attribute__((ext_vector_type(8))) __bf16 bf16x8;
typedef __attribute__((ext_vector_type(4))) __bf16 bf16x4;
typedef __attribute__((ext_vector_type(4))) float f32x4;

constexpr int VOC = 32000;
constexpr int DIM = 512;
constexpr int NH  = 8;
constexpr int HSZ = 64;
constexpr int SEQ = 2048;
constexpr int NB  = 2;
constexpr int NL  = 4;
constexpr int NTOK = NB * SEQ;   // 4096 rows
constexpr int QS  = 3 * DIM;     // qkv weight N
constexpr int QKS = 2 * DIM;     // packed q|k row stride

// async global->LDS, 16B per lane (wave-uniform LDS base + lane*16)
__device__ __forceinline__ void gload16(const void* g, void* lds) {
  __builtin_amdgcn_global_load_lds(
      (const __attribute__((address_space(1))) unsigned int*)g,
      (__attribute__((address_space(3))) unsigned int*)lds, 16, 0, 0);
}

// -------------------------------------- mega: emln rows + ALL weight transposes
__global__ __launch_bounds__(256) void wt_emln(
    const int* __restrict__ idx, const float* __restrict__ tok,
    const float* __restrict__ pos, const float* __restrict__ g1,
    const float* __restrict__ b1v, float* __restrict__ x, bf16* __restrict__ h,
    const float* __restrict__ wq, const float* __restrict__ wk,
    const float* __restrict__ wv, const float* __restrict__ wo,
    const float* __restrict__ w1, const float* __restrict__ w2,
    const float* __restrict__ hw,
    bf16* __restrict__ wqkvT, bf16* __restrict__ woT,
    bf16* __restrict__ w1T, bf16* __restrict__ w2T, bf16* __restrict__ headT) {
  __shared__ float t[64][65];
  __shared__ float s1[4], s2[4];
  int bid = blockIdx.x;
  int tid = threadIdx.x;
  if (bid < NTOK) {
    int row = bid;
    int lane = tid & 63, w = tid >> 6;
    int tt = row & (SEQ - 1);
    int tk = idx[row];
    float a0 = tok[(size_t)tk * DIM + tid] + pos[(size_t)tt * DIM + tid];
    float a1 = tok[(size_t)tk * DIM + tid + 256] + pos[(size_t)tt * DIM + tid + 256];
    x[(size_t)row * DIM + tid] = a0;
    x[(size_t)row * DIM + tid + 256] = a1;
    float ps = a0 + a1, pq = a0 * a0 + a1 * a1;
#pragma unroll
    for (int m = 1; m < 64; m <<= 1) {
      ps += __shfl_xor(ps, m, 64);
      pq += __shfl_xor(pq, m, 64);
    }
    if (lane == 0) { s1[w] = ps; s2[w] = pq; }
    __syncthreads();
    float fs = s1[0] + s1[1] + s1[2] + s1[3];
    float fq = s2[0] + s2[1] + s2[2] + s2[3];
    float mu = fs * (1.0f / DIM);
    float var = fq * (1.0f / DIM) - mu * mu;
    float rs = rsqrtf(var + 1e-5f);
    h[(size_t)row * DIM + tid] = (bf16)((a0 - mu) * rs * g1[tid] + b1v[tid]);
    h[(size_t)row * DIM + tid + 256] =
        (bf16)((a1 - mu) * rs * g1[tid + 256] + b1v[tid + 256]);
    return;
  }
  int wb = bid - NTOK;
  const float* src; bf16* dst; int K, N, n0, k0;
  if (wb < 3072) {
    int l = wb / 768, tt = wb - l * 768;
    if (tt < 256) {
      int which = tt >> 6, u = tt & 63;
      K = DIM; N = DIM;
      n0 = (u & 7) * 64; k0 = (u >> 3) * 64;
      if (which == 0)      { src = wq + (size_t)l * DIM * DIM; dst = wqkvT + (size_t)l * QS * DIM; }
      else if (which == 1) { src = wk + (size_t)l * DIM * DIM; dst = wqkvT + (size_t)l * QS * DIM + DIM * DIM; }
      else if (which == 2) { src = wv + (size_t)l * DIM * DIM; dst = wqkvT + (size_t)l * QS * DIM + 2 * DIM * DIM; }
      else                 { src = wo + (size_t)l * DIM * DIM; dst = woT + (size_t)l * DIM * DIM; }
    } else if (tt < 512) {
      int u = tt - 256;
      K = DIM; N = 4 * DIM;
      n0 = (u & 31) * 64; k0 = (u >> 5) * 64;
      src = w1 + (size_t)l * DIM * 4 * DIM; dst = w1T + (size_t)l * 4 * DIM * DIM;
    } else {
      int u = tt - 512;
      K = 4 * DIM; N = DIM;
      n0 = (u & 7) * 64; k0 = (u >> 3) * 64;
      src = w2 + (size_t)l * 4 * DIM * DIM; dst = w2T + (size_t)l * 4 * DIM * DIM;
    }
  } else {
    int u = wb - 3072;
    K = DIM; N = VOC;
    n0 = (u >> 3) * 64; k0 = (u & 7) * 64;
    src = hw; dst = headT;
  }
  int tx = tid & 63, ty = tid >> 6;
#pragma unroll
  for (int r = 0; r < 16; ++r) {
    int row = ty + r * 4;
    t[row][tx] = src[(size_t)(k0 + row) * N + n0 + tx];
  }
  __syncthreads();
#pragma unroll
  for (int r = 0; r < 16; ++r) {
    int row = ty + r * 4;
    dst[(size_t)(n0 + row) * K + k0 + tx] = (bf16)t[tx][row];
  }
}

// ------------------------------------------- layernorm: wave-per-row, 4/block
__global__ __launch_bounds__(256) void ln_kernel(
    const float* __restrict__ x, const float* __restrict__ g,
    const float* __restrict__ b, bf16* __restrict__ out) {
  int row = blockIdx.x * 4 + (threadIdx.x >> 6);
  int lane = threadIdx.x & 63;
  const float* xr = x + (size_t)row * DIM + lane * 8;
  float4 v0 = *(const float4*)xr;
  float4 v1 = *(const float4*)(xr + 4);
  float ps = v0.x + v0.y + v0.z + v0.w + v1.x + v1.y + v1.z + v1.w;
  float pq = v0.x * v0.x + v0.y * v0.y + v0.z * v0.z + v0.w * v0.w +
             v1.x * v1.x + v1.y * v1.y + v1.z * v1.z + v1.w * v1.w;
#pragma unroll
  for (int m = 1; m < 64; m <<= 1) {
    ps += __shfl_xor(ps, m, 64);
    pq += __shfl_xor(pq, m, 64);
  }
  float mu = ps * (1.0f / DIM);
  float var = pq * (1.0f / DIM) - mu * mu;
  float rs = rsqrtf(var + 1e-5f);
  const float* gp = g + lane * 8;
  const float* bp = b + lane * 8;
  float4 g0 = *(const float4*)gp, g1v = *(const float4*)(gp + 4);
  float4 b0 = *(const float4*)bp, b1v = *(const float4*)(bp + 4);
  bf16x8 o;
  o[0] = (bf16)((v0.x - mu) * rs * g0.x + b0.x);
  o[1] = (bf16)((v0.y - mu) * rs * g0.y + b0.y);
  o[2] = (bf16)((v0.z - mu) * rs * g0.z + b0.z);
  o[3] = (bf16)((v0.w - mu) * rs * g0.w + b0.w);
  o[4] = (bf16)((v1.x - mu) * rs * g1v.x + b1v.x);
  o[5] = (bf16)((v1.y - mu) * rs * g1v.y + b1v.y);
  o[6] = (bf16)((v1.z - mu) * rs * g1v.z + b1v.z);
  o[7] = (bf16)((v1.w - mu) * rs * g1v.w + b1v.w);
  *(bf16x8*)(out + (size_t)row * DIM + lane * 8) = o;
}

// ------------------------------------------------------------- GEMM BMxBN
// 2-barrier m97 loop. DB=true: counted-vmcnt double-buffer — only where
// occupancy arithmetic shows no loss (QKV/wo/ffn1/ffn2, <=2 blocks/CU).
// Head: BN=256, 8 waves, single-buffered (A/B-confirmed best at K=512).
template <int BM, int BN, bool RELU, bool RES, bool OUTB, bool VSPLIT, bool DB>
__global__ __launch_bounds__((BN == 256) ? 512 : 256) void gemm_t(
    const bf16* __restrict__ A, const bf16* __restrict__ Wt,
    const float* __restrict__ bias, const float* __restrict__ res,
    float* __restrict__ outF, bf16* __restrict__ outB, bf16* __restrict__ vTout,
    int K, int N, int ostride) {
  constexpr int NW = (BN == 256) ? 8 : 4;
  constexpr int WN = (BN == 256) ? 4 : (BN == 128) ? 2 : 1;
  constexpr int WM = NW / WN;
  constexpr int MP = BM / WM / 16;
  constexpr int NP = BN / WN / 16;
  constexpr int AJ = (BM * 128) / (NW * 1024);
  constexpr int BJ = (BN * 128) / (NW * 1024);
  constexpr int VC = AJ + BJ;
  static_assert(!DB || VC == 6 || VC == 8, "DB vmcnt supports 6 or 8 loads");
  __shared__ bf16 As[(DB ? 2 : 1) * BM * 64];
  __shared__ bf16 Bs[(DB ? 2 : 1) * BN * 64];
  int tid = threadIdx.x;
  int wid = tid >> 6, ln = tid & 63;
  int lr = ln & 15, lg = ln >> 4;
  int nmt = gridDim.x;
  int bid = blockIdx.y * nmt + blockIdx.x;
  int cpx = (gridDim.x * gridDim.y) >> 3;
  int swz = (bid & 7) * cpx + (bid >> 3);
  int m0 = (swz % nmt) * BM;
  int n0 = (swz / nmt) * BN;
  int wr = wid / WN, wc = wid % WN;
  f32x4 acc[MP][NP] = {};

  const char* Ab = (const char*)A;
  const char* Bb = (const char*)Wt;

  auto STAGE = [&](int k0s, int buf) {
#pragma unroll
    for (int j = 0; j < AJ; ++j) {
      int Lb = j * (NW * 1024) + wid * 1024;
      int L = Lb + ln * 16;
      int row = L >> 7;
      int colb = (L & 127) ^ ((row & 7) << 4);
      gload16(Ab + (size_t)(m0 + row) * (K * 2) + (size_t)k0s * 2 + colb,
              (char*)As + buf * (BM * 128) + Lb);
    }
#pragma unroll
    for (int j = 0; j < BJ; ++j) {
      int Lb = j * (NW * 1024) + wid * 1024;
      int L = Lb + ln * 16;
      int row = L >> 7;
      int colb = (L & 127) ^ ((row & 7) << 4);
      gload16(Bb + (size_t)(n0 + row) * (K * 2) + (size_t)k0s * 2 + colb,
              (char*)Bs + buf * (BN * 128) + Lb);
    }
  };

  if (DB) STAGE(0, 0);
  int cur = 0;
  for (int k0 = 0; k0 < K; k0 += 64) {
    if (!DB) {
      __syncthreads();
      STAGE(k0, 0);
      __syncthreads();
    } else {
      if (k0 + 64 < K) {
        STAGE(k0 + 64, cur ^ 1);
        if constexpr (VC == 6)
          asm volatile("s_waitcnt vmcnt(6)" ::: "memory");
        else
          asm volatile("s_waitcnt vmcnt(8)" ::: "memory");
      } else {
        asm volatile("s_waitcnt vmcnt(0)" ::: "memory");
      }
      __builtin_amdgcn_s_barrier();
    }
#pragma unroll
    for (int kk = 0; kk < 2; ++kk) {
      bf16x8 am[MP], bn[NP];
#pragma unroll
      for (int m = 0; m < MP; ++m) {
        int row = wr * (BM / WM) + m * 16 + lr;
        int cb = (kk * 64 + lg * 16) ^ ((row & 7) << 4);
        am[m] = *(const bf16x8*)((const char*)As + cur * (BM * 128) + row * 128 + cb);
      }
#pragma unroll
      for (int n = 0; n < NP; ++n) {
        int row = wc * (BN / WN) + n * 16 + lr;
        int cb = (kk * 64 + lg * 16) ^ ((row & 7) << 4);
        bn[n] = *(const bf16x8*)((const char*)Bs + cur * (BN * 128) + row * 128 + cb);
      }
#pragma unroll
      for (int m = 0; m < MP; ++m)
#pragma unroll
        for (int n = 0; n < NP; ++n)
          acc[m][n] = __builtin_amdgcn_mfma_f32_16x16x32_bf16(
              am[m], bn[n], acc[m][n], 0, 0, 0);
    }
    if (DB) {
      __builtin_amdgcn_s_barrier();
      cur ^= 1;
    }
  }

  if (VSPLIT && n0 >= 2 * DIM) {
#pragma unroll
    for (int m = 0; m < MP; ++m) {
      int mrow = m0 + wr * (BM / WM) + m * 16 + lg * 4;
      int bb = mrow >> 11, tt = mrow & (SEQ - 1);
#pragma unroll
      for (int n = 0; n < NP; ++n) {
        int d = n0 + wc * (BN / WN) + n * 16 + lr - 2 * DIM;
        bf16x4 pk;
#pragma unroll
        for (int i = 0; i < 4; ++i) pk[i] = (bf16)acc[m][n][i];
        *(bf16x4*)(vTout + ((size_t)(bb * NH + (d >> 6)) * HSZ + (d & 63)) * SEQ + tt) = pk;
      }
    }
    return;
  }

  // q columns: fold 0.125 scale AND log2(e) so fattn can use native exp2
  float qscale = (VSPLIT && n0 < DIM) ? 0.125f * 1.44269504f : 1.0f;
#pragma unroll
  for (int m = 0; m < MP; ++m) {
    int mrow = m0 + wr * (BM / WM) + m * 16 + lg * 4;
#pragma unroll
    for (int n = 0; n < NP; ++n) {
      int nc = n0 + wc * (BN / WN) + n * 16 + lr;
      float bval = bias ? bias[nc] : 0.0f;
#pragma unroll
      for (int i = 0; i < 4; ++i) {
        int mm = mrow + i;
        float val = acc[m][n][i] * qscale + bval;
        if (RELU) val = fmaxf(val, 0.0f);
        if (RES) val += res[(size_t)mm * ostride + nc];
        if (OUTB) outB[(size_t)mm * ostride + nc] = (bf16)val;
        else      outF[(size_t)mm * ostride + nc] = val;
      }
    }
  }
}

// ---------------------------------------------------------------- flash attn
// R16-proven: 512 blocks (4 waves, 64 q-rows), KVBLK=64, dbuf K/V via gload16
// + counted vmcnt(4). XCD remap + deterministic 33-tile CU pairing.
// Softmax in base-2 (log2e folded into QKV q-scale): p = exp2(s2), identical
// ratios to exp(s); masked exp2(-1e30) = 0. T5 setprio around MFMA clusters.
__global__ __launch_bounds__(256) void fattn_kernel(
    const bf16* __restrict__ qk, const bf16* __restrict__ vT,
    bf16* __restrict__ att) {
  __shared__ bf16 Ks[2][64 * 64];
  __shared__ bf16 Vs[2][64 * 64];
  __shared__ bf16 Pl[4][16][72];
  int tid = threadIdx.x;
  int wave = tid >> 6, lane = tid & 63;
  int lr = lane & 15, lg = lane >> 4;
  int linear = blockIdx.x + 32 * (blockIdx.y + 8 * blockIdx.z);  // 0..511
  int swz = (linear & 7) * 64 + (linear >> 3);                   // XCD chunks
  int qtile = swz & 31;
  int hb = swz >> 5;                 // 0..15
  if (hb & 1) qtile = 31 - qtile;    // pair CU loads: (c+1)+(32-c)=33 tiles
  int h = hb & 7, b = hb >> 3;
  int qt0 = qtile * 64;
  const bf16* qb = qk + ((size_t)b * SEQ) * QKS + h * HSZ;
  const char* kb = (const char*)(qb + DIM);
  const char* vb = (const char*)(vT + (size_t)(b * NH + h) * HSZ * SEQ);

  bf16x8 aq[2];
  {
    const bf16* qr = qb + (size_t)(qt0 + wave * 16 + lr) * QKS + lg * 8;
    aq[0] = *(const bf16x8*)qr;
    aq[1] = *(const bf16x8*)(qr + 32);
  }

  f32x4 accO[4] = {};
  float l_r[4] = {0.f, 0.f, 0.f, 0.f};

  int ntile = qtile + 1;
#define STAGE(ti, buf)                                                        \
  {                                                                           \
    _Pragma("unroll")                                                         \
    for (int j = 0; j < 2; ++j) {                                             \
      int Lb = j * 4096 + wave * 1024;                                        \
      int L = Lb + lane * 16;                                                 \
      int row = L >> 7;                                                       \
      int cb = (L & 127) ^ ((row & 7) << 4);                                  \
      gload16(kb + (size_t)((ti) * 64 + row) * (QKS * 2) + cb,                \
              (char*)Ks[buf] + Lb);                                           \
      gload16(vb + (size_t)row * (SEQ * 2) + (ti) * 128 + cb,                 \
              (char*)Vs[buf] + Lb);                                           \
    }                                                                         \
  }

  STAGE(0, 0);
  int cur = 0;
  for (int ti = 0; ti < ntile; ++ti) {
    if (ti + 1 < ntile) {
      STAGE(ti + 1, cur ^ 1);
      asm volatile("s_waitcnt vmcnt(4)" ::: "memory");
    } else {
      asm volatile("s_waitcnt vmcnt(0)" ::: "memory");
    }
    __builtin_amdgcn_s_barrier();
    int kv0 = ti * 64;
    bool diag = (ti == ntile - 1);

    f32x4 sc[4];
    __builtin_amdgcn_s_setprio(1);
#pragma unroll
    for (int s = 0; s < 4; ++s) {
      int row = s * 16 + lr;
      const char* base = (const char*)Ks[cur] + row * 128;
      bf16x8 b0 = *(const bf16x8*)(base + ((lg * 16) ^ ((row & 7) << 4)));
      bf16x8 b1 = *(const bf16x8*)(base + ((64 + lg * 16) ^ ((row & 7) << 4)));
      f32x4 z = {};
      z = __builtin_amdgcn_mfma_f32_16x16x32_bf16(aq[0], b0, z, 0, 0, 0);
      sc[s] = __builtin_amdgcn_mfma_f32_16x16x32_bf16(aq[1], b1, z, 0, 0, 0);
    }
    __builtin_amdgcn_s_setprio(0);

#pragma unroll
    for (int i = 0; i < 4; ++i) {
      if (diag) {
        int qrow = qt0 + wave * 16 + lg * 4 + i;
#pragma unroll
        for (int s = 0; s < 4; ++s) {
          int kvc = kv0 + s * 16 + lr;
          if (kvc > qrow) sc[s][i] = -1e30f;
        }
      }
      float rs = 0.f;
#pragma unroll
      for (int s = 0; s < 4; ++s) {
        float p = exp2f(sc[s][i]);
        sc[s][i] = p;
        rs += p;
      }
      rs += __shfl_xor(rs, 1, 64);
      rs += __shfl_xor(rs, 2, 64);
      rs += __shfl_xor(rs, 4, 64);
      rs += __shfl_xor(rs, 8, 64);
      l_r[i] += rs;
    }

#pragma unroll
    for (int i = 0; i < 4; ++i)
#pragma unroll
      for (int s = 0; s < 4; ++s)
        Pl[wave][lg * 4 + i][s * 16 + lr] = (bf16)sc[s][i];
    bf16x8 pa0 = *(const bf16x8*)&Pl[wave][lr][lg * 8];
    bf16x8 pa1 = *(const bf16x8*)&Pl[wave][lr][32 + lg * 8];

    __builtin_amdgcn_s_setprio(1);
#pragma unroll
    for (int ds = 0; ds < 4; ++ds) {
      int row = ds * 16 + lr;
      const char* base = (const char*)Vs[cur] + row * 128;
      bf16x8 v0 = *(const bf16x8*)(base + ((lg * 16) ^ ((row & 7) << 4)));
      bf16x8 v1 = *(const bf16x8*)(base + ((64 + lg * 16) ^ ((row & 7) << 4)));
      accO[ds] = __builtin_amdgcn_mfma_f32_16x16x32_bf16(pa0, v0, accO[ds], 0, 0, 0);
      accO[ds] = __builtin_amdgcn_mfma_f32_16x16x32_bf16(pa1, v1, accO[ds], 0, 0, 0);
    }
    __builtin_amdgcn_s_setprio(0);
    __builtin_amdgcn_s_barrier();
    cur ^= 1;
  }
#undef STAGE

#pragma unroll
  for (int i = 0; i < 4; ++i) {
    float inv = 1.0f / l_r[i];
    size_t orow = ((size_t)b * SEQ + qt0 + wave * 16 + lg * 4 + i) * DIM + h * HSZ;
#pragma unroll
    for (int ds = 0; ds < 4; ++ds)
      att[orow + ds * 16 + lr] = (bf16)(accO[ds][i] * inv);
  }
}

// ---------------------------------------------------------------- launcher
extern "C" void kernel_launch(void* const* d_in, const int* in_sizes, int n_in,
                              void* d_out, int out_size, void* d_ws, size_t ws_size,
                              hipStream_t stream) {
  const int*   idx    = (const int*)d_in[0];
  const float* tok    = (const float*)d_in[1];
  const float* pos    = (const float*)d_in[2];
  const float* ln1_g  = (const float*)d_in[3];
  const float* ln1_b  = (const float*)d_in[4];
  const float* wq     = (const float*)d_in[5];
  const float* wk     = (const float*)d_in[6];
  const float* wv     = (const float*)d_in[7];
  const float* wo     = (const float*)d_in[8];
  const float* bo     = (const float*)d_in[9];
  const float* ln2_g  = (const float*)d_in[10];
  const float* ln2_b  = (const float*)d_in[11];
  const float* w1     = (const float*)d_in[12];
  const float* b1     = (const float*)d_in[13];
  const float* w2     = (const float*)d_in[14];
  const float* b2     = (const float*)d_in[15];
  const float* lnf_g  = (const float*)d_in[16];
  const float* lnf_b  = (const float*)d_in[17];
  const float* head_w = (const float*)d_in[18];
  const float* head_b = (const float*)d_in[19];

  char* W = (char*)d_ws;
  float* x     = (float*)(W);                 // [4096][512] f32    8 MB
  bf16*  h     = (bf16*)(W + 8388608);        // [4096][512]        4 MB
  bf16*  qk    = (bf16*)(W + 12582912);       // [4096][1024]       8 MB
  bf16*  vTb   = (bf16*)(W + 20971520);       // [2][8][64][2048]   4 MB
  bf16*  attb  = (bf16*)(W + 25165824);       // [4096][512]        4 MB
  bf16*  ffn   = (bf16*)(W + 29360128);       // [4096][2048]      16 MB
  bf16*  wqkvT = (bf16*)(W + 46137344);       // 4L x [1536][512]   6 MB
  bf16*  woT   = (bf16*)(W + 52428800);       // 4L x [512][512]    2 MB
  bf16*  w1T   = (bf16*)(W + 54525952);       // 4L x [2048][512]   8 MB
  bf16*  w2T   = (bf16*)(W + 62914560);       // 4L x [512][2048]   8 MB
  bf16*  headT = (bf16*)(W + 71303168);       // [32000][512]      ~31.3 MB

  wt_emln<<<NTOK + 3072 + 4000, 256, 0, stream>>>(
      idx, tok, pos, ln1_g, ln1_b, x, h,
      wq, wk, wv, wo, w1, w2, head_w, wqkvT, woT, w1T, w2T, headT);

  dim3 gQKV(NTOK / 128, QS / 128);        // (32, 12)
  dim3 gD64(NTOK / 128, DIM / 64);        // (32, 8)
  dim3 gF1(NTOK / 128, 4 * DIM / 128);    // (32, 16)
  dim3 gV(NTOK / 128, VOC / 256);         // (32, 125)  BN=256 head (confirmed)
  dim3 gA(SEQ / 64, NH, NB);              // (32, 8, 2) QBLK=64 (confirmed)

  for (int l = 0; l < NL; ++l) {
    if (l > 0)
      ln_kernel<<<NTOK / 4, 256, 0, stream>>>(x, ln1_g + l * DIM, ln1_b + l * DIM, h);
    gemm_t<128, 128, false, false, true, true, true><<<gQKV, 256, 0, stream>>>(
        h, wqkvT + (size_t)l * QS * DIM, nullptr, nullptr, nullptr, qk, vTb,
        DIM, QS, QKS);
    fattn_kernel<<<gA, 256, 0, stream>>>(qk, vTb, attb);
    gemm_t<128, 64, false, true, false, false, true><<<gD64, 256, 0, stream>>>(
        attb, woT + (size_t)l * DIM * DIM, bo + l * DIM, x, x, nullptr, nullptr,
        DIM, DIM, DIM);
    ln_kernel<<<NTOK / 4, 256, 0, stream>>>(x, ln2_g + l * DIM, ln2_b + l * DIM, h);
    gemm_t<128, 128, true, false, true, false, true><<<gF1, 256, 0, stream>>>(
        h, w1T + (size_t)l * 4 * DIM * DIM, b1 + (size_t)l * 4 * DIM, nullptr,
        nullptr, ffn, nullptr, DIM, 4 * DIM, 4 * DIM);
    gemm_t<128, 64, false, true, false, false, true><<<gD64, 256, 0, stream>>>(
        ffn, w2T + (size_t)l * 4 * DIM * DIM, b2 + l * DIM, x, x, nullptr,
        nullptr, 4 * DIM, DIM, DIM);
  }

  ln_kernel<<<NTOK / 4, 256, 0, stream>>>(x, lnf_g, lnf_b, h);
  gemm_t<128, 256, false, false, false, false, false><<<gV, 512, 0, stream>>>(
      h, headT, head_b, nullptr, (float*)d_out, nullptr, nullptr, DIM, VOC, VOC);
}

// Round 20
// 782.774 us; speedup vs baseline: 1.0846x; 1.0210x over previous
//
#include <hip/hip_runtime.h>
#include <hip/hip_bf16.h>
#include <cstddef>

typedef __bf16 bf16;
typedef __attribute__((ext_vector_type(8))) __bf16 bf16x8;
typedef __attribute__((ext_vector_type(4))) __bf16 bf16x4;
typedef __attribute__((ext_vector_type(4))) float f32x4;

constexpr int VOC = 32000;
constexpr int DIM = 512;
constexpr int NH  = 8;
constexpr int HSZ = 64;
constexpr int SEQ = 2048;
constexpr int NB  = 2;
constexpr int NL  = 4;
constexpr int NTOK = NB * SEQ;   // 4096 rows
constexpr int QS  = 3 * DIM;     // qkv weight N
constexpr int QKS = 2 * DIM;     // packed q|k row stride

// async global->LDS, 16B per lane (wave-uniform LDS base + lane*16)
__device__ __forceinline__ void gload16(const void* g, void* lds) {
  __builtin_amdgcn_global_load_lds(
      (const __attribute__((address_space(1))) unsigned int*)g,
      (__attribute__((address_space(3))) unsigned int*)lds, 16, 0, 0);
}

// -------------------------------------- mega: emln rows + ALL weight transposes
__global__ __launch_bounds__(256) void wt_emln(
    const int* __restrict__ idx, const float* __restrict__ tok,
    const float* __restrict__ pos, const float* __restrict__ g1,
    const float* __restrict__ b1v, float* __restrict__ x, bf16* __restrict__ h,
    const float* __restrict__ wq, const float* __restrict__ wk,
    const float* __restrict__ wv, const float* __restrict__ wo,
    const float* __restrict__ w1, const float* __restrict__ w2,
    const float* __restrict__ hw,
    bf16* __restrict__ wqkvT, bf16* __restrict__ woT,
    bf16* __restrict__ w1T, bf16* __restrict__ w2T, bf16* __restrict__ headT) {
  __shared__ float t[64][65];
  __shared__ float s1[4], s2[4];
  int bid = blockIdx.x;
  int tid = threadIdx.x;
  if (bid < NTOK) {
    int row = bid;
    int lane = tid & 63, w = tid >> 6;
    int tt = row & (SEQ - 1);
    int tk = idx[row];
    float a0 = tok[(size_t)tk * DIM + tid] + pos[(size_t)tt * DIM + tid];
    float a1 = tok[(size_t)tk * DIM + tid + 256] + pos[(size_t)tt * DIM + tid + 256];
    x[(size_t)row * DIM + tid] = a0;
    x[(size_t)row * DIM + tid + 256] = a1;
    float ps = a0 + a1, pq = a0 * a0 + a1 * a1;
#pragma unroll
    for (int m = 1; m < 64; m <<= 1) {
      ps += __shfl_xor(ps, m, 64);
      pq += __shfl_xor(pq, m, 64);
    }
    if (lane == 0) { s1[w] = ps; s2[w] = pq; }
    __syncthreads();
    float fs = s1[0] + s1[1] + s1[2] + s1[3];
    float fq = s2[0] + s2[1] + s2[2] + s2[3];
    float mu = fs * (1.0f / DIM);
    float var = fq * (1.0f / DIM) - mu * mu;
    float rs = rsqrtf(var + 1e-5f);
    h[(size_t)row * DIM + tid] = (bf16)((a0 - mu) * rs * g1[tid] + b1v[tid]);
    h[(size_t)row * DIM + tid + 256] =
        (bf16)((a1 - mu) * rs * g1[tid + 256] + b1v[tid + 256]);
    return;
  }
  int wb = bid - NTOK;
  const float* src; bf16* dst; int K, N, n0, k0;
  if (wb < 3072) {
    int l = wb / 768, tt = wb - l * 768;
    if (tt < 256) {
      int which = tt >> 6, u = tt & 63;
      K = DIM; N = DIM;
      n0 = (u & 7) * 64; k0 = (u >> 3) * 64;
      if (which == 0)      { src = wq + (size_t)l * DIM * DIM; dst = wqkvT + (size_t)l * QS * DIM; }
      else if (which == 1) { src = wk + (size_t)l * DIM * DIM; dst = wqkvT + (size_t)l * QS * DIM + DIM * DIM; }
      else if (which == 2) { src = wv + (size_t)l * DIM * DIM; dst = wqkvT + (size_t)l * QS * DIM + 2 * DIM * DIM; }
      else                 { src = wo + (size_t)l * DIM * DIM; dst = woT + (size_t)l * DIM * DIM; }
    } else if (tt < 512) {
      int u = tt - 256;
      K = DIM; N = 4 * DIM;
      n0 = (u & 31) * 64; k0 = (u >> 5) * 64;
      src = w1 + (size_t)l * DIM * 4 * DIM; dst = w1T + (size_t)l * 4 * DIM * DIM;
    } else {
      int u = tt - 512;
      K = 4 * DIM; N = DIM;
      n0 = (u & 7) * 64; k0 = (u >> 3) * 64;
      src = w2 + (size_t)l * 4 * DIM * DIM; dst = w2T + (size_t)l * 4 * DIM * DIM;
    }
  } else {
    int u = wb - 3072;
    K = DIM; N = VOC;
    n0 = (u >> 3) * 64; k0 = (u & 7) * 64;
    src = hw; dst = headT;
  }
  int tx = tid & 63, ty = tid >> 6;
#pragma unroll
  for (int r = 0; r < 16; ++r) {
    int row = ty + r * 4;
    t[row][tx] = src[(size_t)(k0 + row) * N + n0 + tx];
  }
  __syncthreads();
#pragma unroll
  for (int r = 0; r < 16; ++r) {
    int row = ty + r * 4;
    dst[(size_t)(n0 + row) * K + k0 + tx] = (bf16)t[tx][row];
  }
}

// ------------------------------------------- layernorm: wave-per-row, 4/block
__global__ __launch_bounds__(256) void ln_kernel(
    const float* __restrict__ x, const float* __restrict__ g,
    const float* __restrict__ b, bf16* __restrict__ out) {
  int row = blockIdx.x * 4 + (threadIdx.x >> 6);
  int lane = threadIdx.x & 63;
  const float* xr = x + (size_t)row * DIM + lane * 8;
  float4 v0 = *(const float4*)xr;
  float4 v1 = *(const float4*)(xr + 4);
  float ps = v0.x + v0.y + v0.z + v0.w + v1.x + v1.y + v1.z + v1.w;
  float pq = v0.x * v0.x + v0.y * v0.y + v0.z * v0.z + v0.w * v0.w +
             v1.x * v1.x + v1.y * v1.y + v1.z * v1.z + v1.w * v1.w;
#pragma unroll
  for (int m = 1; m < 64; m <<= 1) {
    ps += __shfl_xor(ps, m, 64);
    pq += __shfl_xor(pq, m, 64);
  }
  float mu = ps * (1.0f / DIM);
  float var = pq * (1.0f / DIM) - mu * mu;
  float rs = rsqrtf(var + 1e-5f);
  const float* gp = g + lane * 8;
  const float* bp = b + lane * 8;
  float4 g0 = *(const float4*)gp, g1v = *(const float4*)(gp + 4);
  float4 b0 = *(const float4*)bp, b1v = *(const float4*)(bp + 4);
  bf16x8 o;
  o[0] = (bf16)((v0.x - mu) * rs * g0.x + b0.x);
  o[1] = (bf16)((v0.y - mu) * rs * g0.y + b0.y);
  o[2] = (bf16)((v0.z - mu) * rs * g0.z + b0.z);
  o[3] = (bf16)((v0.w - mu) * rs * g0.w + b0.w);
  o[4] = (bf16)((v1.x - mu) * rs * g1v.x + b1v.x);
  o[5] = (bf16)((v1.y - mu) * rs * g1v.y + b1v.y);
  o[6] = (bf16)((v1.z - mu) * rs * g1v.z + b1v.z);
  o[7] = (bf16)((v1.w - mu) * rs * g1v.w + b1v.w);
  *(bf16x8*)(out + (size_t)row * DIM + lane * 8) = o;
}

// ------------------------------------------------------------- GEMM BMxBN
// 2-barrier m97 loop. DB=true: counted-vmcnt double-buffer — only where
// occupancy arithmetic shows no loss (QKV/wo/ffn1/ffn2, <=2 blocks/CU).
// Head: BN=256, 8 waves, single-buffered (A/B-confirmed best at K=512).
template <int BM, int BN, bool RELU, bool RES, bool OUTB, bool VSPLIT, bool DB>
__global__ __launch_bounds__((BN == 256) ? 512 : 256) void gemm_t(
    const bf16* __restrict__ A, const bf16* __restrict__ Wt,
    const float* __restrict__ bias, const float* __restrict__ res,
    float* __restrict__ outF, bf16* __restrict__ outB, bf16* __restrict__ vTout,
    int K, int N, int ostride) {
  constexpr int NW = (BN == 256) ? 8 : 4;
  constexpr int WN = (BN == 256) ? 4 : (BN == 128) ? 2 : 1;
  constexpr int WM = NW / WN;
  constexpr int MP = BM / WM / 16;
  constexpr int NP = BN / WN / 16;
  constexpr int AJ = (BM * 128) / (NW * 1024);
  constexpr int BJ = (BN * 128) / (NW * 1024);
  constexpr int VC = AJ + BJ;
  static_assert(!DB || VC == 6 || VC == 8, "DB vmcnt supports 6 or 8 loads");
  __shared__ bf16 As[(DB ? 2 : 1) * BM * 64];
  __shared__ bf16 Bs[(DB ? 2 : 1) * BN * 64];
  int tid = threadIdx.x;
  int wid = tid >> 6, ln = tid & 63;
  int lr = ln & 15, lg = ln >> 4;
  int nmt = gridDim.x;
  int bid = blockIdx.y * nmt + blockIdx.x;
  int cpx = (gridDim.x * gridDim.y) >> 3;
  int swz = (bid & 7) * cpx + (bid >> 3);
  int m0 = (swz % nmt) * BM;
  int n0 = (swz / nmt) * BN;
  int wr = wid / WN, wc = wid % WN;
  f32x4 acc[MP][NP] = {};

  const char* Ab = (const char*)A;
  const char* Bb = (const char*)Wt;

  auto STAGE = [&](int k0s, int buf) {
#pragma unroll
    for (int j = 0; j < AJ; ++j) {
      int Lb = j * (NW * 1024) + wid * 1024;
      int L = Lb + ln * 16;
      int row = L >> 7;
      int colb = (L & 127) ^ ((row & 7) << 4);
      gload16(Ab + (size_t)(m0 + row) * (K * 2) + (size_t)k0s * 2 + colb,
              (char*)As + buf * (BM * 128) + Lb);
    }
#pragma unroll
    for (int j = 0; j < BJ; ++j) {
      int Lb = j * (NW * 1024) + wid * 1024;
      int L = Lb + ln * 16;
      int row = L >> 7;
      int colb = (L & 127) ^ ((row & 7) << 4);
      gload16(Bb + (size_t)(n0 + row) * (K * 2) + (size_t)k0s * 2 + colb,
              (char*)Bs + buf * (BN * 128) + Lb);
    }
  };

  if (DB) STAGE(0, 0);
  int cur = 0;
  for (int k0 = 0; k0 < K; k0 += 64) {
    if (!DB) {
      __syncthreads();
      STAGE(k0, 0);
      __syncthreads();
    } else {
      if (k0 + 64 < K) {
        STAGE(k0 + 64, cur ^ 1);
        if constexpr (VC == 6)
          asm volatile("s_waitcnt vmcnt(6)" ::: "memory");
        else
          asm volatile("s_waitcnt vmcnt(8)" ::: "memory");
      } else {
        asm volatile("s_waitcnt vmcnt(0)" ::: "memory");
      }
      __builtin_amdgcn_s_barrier();
    }
#pragma unroll
    for (int kk = 0; kk < 2; ++kk) {
      bf16x8 am[MP], bn[NP];
#pragma unroll
      for (int m = 0; m < MP; ++m) {
        int row = wr * (BM / WM) + m * 16 + lr;
        int cb = (kk * 64 + lg * 16) ^ ((row & 7) << 4);
        am[m] = *(const bf16x8*)((const char*)As + cur * (BM * 128) + row * 128 + cb);
      }
#pragma unroll
      for (int n = 0; n < NP; ++n) {
        int row = wc * (BN / WN) + n * 16 + lr;
        int cb = (kk * 64 + lg * 16) ^ ((row & 7) << 4);
        bn[n] = *(const bf16x8*)((const char*)Bs + cur * (BN * 128) + row * 128 + cb);
      }
#pragma unroll
      for (int m = 0; m < MP; ++m)
#pragma unroll
        for (int n = 0; n < NP; ++n)
          acc[m][n] = __builtin_amdgcn_mfma_f32_16x16x32_bf16(
              am[m], bn[n], acc[m][n], 0, 0, 0);
    }
    if (DB) {
      __builtin_amdgcn_s_barrier();
      cur ^= 1;
    }
  }

  if (VSPLIT && n0 >= 2 * DIM) {
#pragma unroll
    for (int m = 0; m < MP; ++m) {
      int mrow = m0 + wr * (BM / WM) + m * 16 + lg * 4;
      int bb = mrow >> 11, tt = mrow & (SEQ - 1);
#pragma unroll
      for (int n = 0; n < NP; ++n) {
        int d = n0 + wc * (BN / WN) + n * 16 + lr - 2 * DIM;
        bf16x4 pk;
#pragma unroll
        for (int i = 0; i < 4; ++i) pk[i] = (bf16)acc[m][n][i];
        *(bf16x4*)(vTout + ((size_t)(bb * NH + (d >> 6)) * HSZ + (d & 63)) * SEQ + tt) = pk;
      }
    }
    return;
  }

  float qscale = (VSPLIT && n0 < DIM) ? 0.125f : 1.0f;  // fold QK^T scale into q
#pragma unroll
  for (int m = 0; m < MP; ++m) {
    int mrow = m0 + wr * (BM / WM) + m * 16 + lg * 4;
#pragma unroll
    for (int n = 0; n < NP; ++n) {
      int nc = n0 + wc * (BN / WN) + n * 16 + lr;
      float bval = bias ? bias[nc] : 0.0f;
#pragma unroll
      for (int i = 0; i < 4; ++i) {
        int mm = mrow + i;
        float val = acc[m][n][i] * qscale + bval;
        if (RELU) val = fmaxf(val, 0.0f);
        if (RES) val += res[(size_t)mm * ostride + nc];
        if (OUTB) outB[(size_t)mm * ostride + nc] = (bf16)val;
        else      outF[(size_t)mm * ostride + nc] = val;
      }
    }
  }
}

// ---------------------------------------------------------------- flash attn
// R16-proven: 512 blocks (4 waves, 64 q-rows), KVBLK=64, dbuf K/V via gload16
// + counted vmcnt(4). XCD remap + deterministic 33-tile CU pairing.
// Max-free softmax (s pre-scaled in QKV epilogue); T5 setprio.
__global__ __launch_bounds__(256) void fattn_kernel(
    const bf16* __restrict__ qk, const bf16* __restrict__ vT,
    bf16* __restrict__ att) {
  __shared__ bf16 Ks[2][64 * 64];
  __shared__ bf16 Vs[2][64 * 64];
  __shared__ bf16 Pl[4][16][72];
  int tid = threadIdx.x;
  int wave = tid >> 6, lane = tid & 63;
  int lr = lane & 15, lg = lane >> 4;
  int linear = blockIdx.x + 32 * (blockIdx.y + 8 * blockIdx.z);  // 0..511
  int swz = (linear & 7) * 64 + (linear >> 3);                   // XCD chunks
  int qtile = swz & 31;
  int hb = swz >> 5;                 // 0..15
  if (hb & 1) qtile = 31 - qtile;    // pair CU loads: (c+1)+(32-c)=33 tiles
  int h = hb & 7, b = hb >> 3;
  int qt0 = qtile * 64;
  const bf16* qb = qk + ((size_t)b * SEQ) * QKS + h * HSZ;
  const char* kb = (const char*)(qb + DIM);
  const char* vb = (const char*)(vT + (size_t)(b * NH + h) * HSZ * SEQ);

  bf16x8 aq[2];
  {
    const bf16* qr = qb + (size_t)(qt0 + wave * 16 + lr) * QKS + lg * 8;
    aq[0] = *(const bf16x8*)qr;
    aq[1] = *(const bf16x8*)(qr + 32);
  }

  f32x4 accO[4] = {};
  float l_r[4] = {0.f, 0.f, 0.f, 0.f};

  int ntile = qtile + 1;
#define STAGE(ti, buf)                                                        \
  {                                                                           \
    _Pragma("unroll")                                                         \
    for (int j = 0; j < 2; ++j) {                                             \
      int Lb = j * 4096 + wave * 1024;                                        \
      int L = Lb + lane * 16;                                                 \
      int row = L >> 7;                                                       \
      int cb = (L & 127) ^ ((row & 7) << 4);                                  \
      gload16(kb + (size_t)((ti) * 64 + row) * (QKS * 2) + cb,                \
              (char*)Ks[buf] + Lb);                                           \
      gload16(vb + (size_t)row * (SEQ * 2) + (ti) * 128 + cb,                 \
              (char*)Vs[buf] + Lb);                                           \
    }                                                                         \
  }

  STAGE(0, 0);
  int cur = 0;
  for (int ti = 0; ti < ntile; ++ti) {
    if (ti + 1 < ntile) {
      STAGE(ti + 1, cur ^ 1);
      asm volatile("s_waitcnt vmcnt(4)" ::: "memory");
    } else {
      asm volatile("s_waitcnt vmcnt(0)" ::: "memory");
    }
    __builtin_amdgcn_s_barrier();
    int kv0 = ti * 64;
    bool diag = (ti == ntile - 1);

    f32x4 sc[4];
    __builtin_amdgcn_s_setprio(1);
#pragma unroll
    for (int s = 0; s < 4; ++s) {
      int row = s * 16 + lr;
      const char* base = (const char*)Ks[cur] + row * 128;
      bf16x8 b0 = *(const bf16x8*)(base + ((lg * 16) ^ ((row & 7) << 4)));
      bf16x8 b1 = *(const bf16x8*)(base + ((64 + lg * 16) ^ ((row & 7) << 4)));
      f32x4 z = {};
      z = __builtin_amdgcn_mfma_f32_16x16x32_bf16(aq[0], b0, z, 0, 0, 0);
      sc[s] = __builtin_amdgcn_mfma_f32_16x16x32_bf16(aq[1], b1, z, 0, 0, 0);
    }
    __builtin_amdgcn_s_setprio(0);

#pragma unroll
    for (int i = 0; i < 4; ++i) {
      if (diag) {
        int qrow = qt0 + wave * 16 + lg * 4 + i;
#pragma unroll
        for (int s = 0; s < 4; ++s) {
          int kvc = kv0 + s * 16 + lr;
          if (kvc > qrow) sc[s][i] = -1e30f;
        }
      }
      float rs = 0.f;
#pragma unroll
      for (int s = 0; s < 4; ++s) {
        float p = __expf(sc[s][i]);
        sc[s][i] = p;
        rs += p;
      }
      rs += __shfl_xor(rs, 1, 64);
      rs += __shfl_xor(rs, 2, 64);
      rs += __shfl_xor(rs, 4, 64);
      rs += __shfl_xor(rs, 8, 64);
      l_r[i] += rs;
    }

#pragma unroll
    for (int i = 0; i < 4; ++i)
#pragma unroll
      for (int s = 0; s < 4; ++s)
        Pl[wave][lg * 4 + i][s * 16 + lr] = (bf16)sc[s][i];
    bf16x8 pa0 = *(const bf16x8*)&Pl[wave][lr][lg * 8];
    bf16x8 pa1 = *(const bf16x8*)&Pl[wave][lr][32 + lg * 8];

    __builtin_amdgcn_s_setprio(1);
#pragma unroll
    for (int ds = 0; ds < 4; ++ds) {
      int row = ds * 16 + lr;
      const char* base = (const char*)Vs[cur] + row * 128;
      bf16x8 v0 = *(const bf16x8*)(base + ((lg * 16) ^ ((row & 7) << 4)));
      bf16x8 v1 = *(const bf16x8*)(base + ((64 + lg * 16) ^ ((row & 7) << 4)));
      accO[ds] = __builtin_amdgcn_mfma_f32_16x16x32_bf16(pa0, v0, accO[ds], 0, 0, 0);
      accO[ds] = __builtin_amdgcn_mfma_f32_16x16x32_bf16(pa1, v1, accO[ds], 0, 0, 0);
    }
    __builtin_amdgcn_s_setprio(0);
    __builtin_amdgcn_s_barrier();
    cur ^= 1;
  }
#undef STAGE

#pragma unroll
  for (int i = 0; i < 4; ++i) {
    float inv = 1.0f / l_r[i];
    size_t orow = ((size_t)b * SEQ + qt0 + wave * 16 + lg * 4 + i) * DIM + h * HSZ;
#pragma unroll
    for (int ds = 0; ds < 4; ++ds)
      att[orow + ds * 16 + lr] = (bf16)(accO[ds][i] * inv);
  }
}

// ---------------------------------------------------------------- launcher
extern "C" void kernel_launch(void* const* d_in, const int* in_sizes, int n_in,
                              void* d_out, int out_size, void* d_ws, size_t ws_size,
                              hipStream_t stream) {
  const int*   idx    = (const int*)d_in[0];
  const float* tok    = (const float*)d_in[1];
  const float* pos    = (const float*)d_in[2];
  const float* ln1_g  = (const float*)d_in[3];
  const float* ln1_b  = (const float*)d_in[4];
  const float* wq     = (const float*)d_in[5];
  const float* wk     = (const float*)d_in[6];
  const float* wv     = (const float*)d_in[7];
  const float* wo     = (const float*)d_in[8];
  const float* bo     = (const float*)d_in[9];
  const float* ln2_g  = (const float*)d_in[10];
  const float* ln2_b  = (const float*)d_in[11];
  const float* w1     = (const float*)d_in[12];
  const float* b1     = (const float*)d_in[13];
  const float* w2     = (const float*)d_in[14];
  const float* b2     = (const float*)d_in[15];
  const float* lnf_g  = (const float*)d_in[16];
  const float* lnf_b  = (const float*)d_in[17];
  const float* head_w = (const float*)d_in[18];
  const float* head_b = (const float*)d_in[19];

  char* W = (char*)d_ws;
  float* x     = (float*)(W);                 // [4096][512] f32    8 MB
  bf16*  h     = (bf16*)(W + 8388608);        // [4096][512]        4 MB
  bf16*  qk    = (bf16*)(W + 12582912);       // [4096][1024]       8 MB
  bf16*  vTb   = (bf16*)(W + 20971520);       // [2][8][64][2048]   4 MB
  bf16*  attb  = (bf16*)(W + 25165824);       // [4096][512]        4 MB
  bf16*  ffn   = (bf16*)(W + 29360128);       // [4096][2048]      16 MB
  bf16*  wqkvT = (bf16*)(W + 46137344);       // 4L x [1536][512]   6 MB
  bf16*  woT   = (bf16*)(W + 52428800);       // 4L x [512][512]    2 MB
  bf16*  w1T   = (bf16*)(W + 54525952);       // 4L x [2048][512]   8 MB
  bf16*  w2T   = (bf16*)(W + 62914560);       // 4L x [512][2048]   8 MB
  bf16*  headT = (bf16*)(W + 71303168);       // [32000][512]      ~31.3 MB

  wt_emln<<<NTOK + 3072 + 4000, 256, 0, stream>>>(
      idx, tok, pos, ln1_g, ln1_b, x, h,
      wq, wk, wv, wo, w1, w2, head_w, wqkvT, woT, w1T, w2T, headT);

  dim3 gQKV(NTOK / 128, QS / 128);        // (32, 12)
  dim3 gD64(NTOK / 128, DIM / 64);        // (32, 8)
  dim3 gF1(NTOK / 128, 4 * DIM / 128);    // (32, 16)
  dim3 gV(NTOK / 128, VOC / 256);         // (32, 125)  BN=256 head (confirmed)
  dim3 gA(SEQ / 64, NH, NB);              // (32, 8, 2) QBLK=64 (confirmed)

  for (int l = 0; l < NL; ++l) {
    if (l > 0)
      ln_kernel<<<NTOK / 4, 256, 0, stream>>>(x, ln1_g + l * DIM, ln1_b + l * DIM, h);
    gemm_t<128, 128, false, false, true, true, true><<<gQKV, 256, 0, stream>>>(
        h, wqkvT + (size_t)l * QS * DIM, nullptr, nullptr, nullptr, qk, vTb,
        DIM, QS, QKS);
    fattn_kernel<<<gA, 256, 0, stream>>>(qk, vTb, attb);
    gemm_t<128, 64, false, true, false, false, true><<<gD64, 256, 0, stream>>>(
        attb, woT + (size_t)l * DIM * DIM, bo + l * DIM, x, x, nullptr, nullptr,
        DIM, DIM, DIM);
    ln_kernel<<<NTOK / 4, 256, 0, stream>>>(x, ln2_g + l * DIM, ln2_b + l * DIM, h);
    gemm_t<128, 128, true, false, true, false, true><<<gF1, 256, 0, stream>>>(
        h, w1T + (size_t)l * 4 * DIM * DIM, b1 + (size_t)l * 4 * DIM, nullptr,
        nullptr, ffn, nullptr, DIM, 4 * DIM, 4 * DIM);
    gemm_t<128, 64, false, true, false, false, true><<<gD64, 256, 0, stream>>>(
        ffn, w2T + (size_t)l * 4 * DIM * DIM, b2 + l * DIM, x, x, nullptr,
        nullptr, 4 * DIM, DIM, DIM);
  }

  ln_kernel<<<NTOK / 4, 256, 0, stream>>>(x, lnf_g, lnf_b, h);
  gemm_t<128, 256, false, false, false, false, false><<<gV, 512, 0, stream>>>(
      h, headT, head_b, nullptr, (float*)d_out, nullptr, nullptr, DIM, VOC, VOC);
}